// Round 14
// baseline (685.896 us; speedup 1.0000x reference)
//
#include <hip/hip_runtime.h>

// Problem dims
#define B_    8
#define N_    1024
#define DIN   512
#define H_    8
#define DH    64
#define DQKV  6144   // 2*DQ + 2*DQ + DV = 512+512+512+512+4096
#define DEXP  2048
#define DTIME 256

typedef __attribute__((ext_vector_type(8))) short s16x8;   // 8 bf16 (MFMA A/B frag)
typedef __attribute__((ext_vector_type(4))) short s16x4;
typedef __attribute__((ext_vector_type(4))) float f32x4;   // MFMA C/D frag

__device__ __forceinline__ unsigned short f2bf(float f) {
  unsigned int u = __float_as_uint(f);
  u = (u + 0x7fffu + ((u >> 16) & 1u)) >> 16;   // RNE
  return (unsigned short)u;
}

__device__ __forceinline__ void gload_lds16(const unsigned short* g, unsigned short* l) {
  __builtin_amdgcn_global_load_lds(
      (const __attribute__((address_space(1))) unsigned int*)(g),
      (__attribute__((address_space(3))) unsigned int*)(l), 16, 0, 0);
}

#define WAITV(n) do { asm volatile("s_waitcnt vmcnt(" #n ")" ::: "memory"); \
                      __builtin_amdgcn_sched_barrier(0); } while (0)
#define WAITL0() do { asm volatile("s_waitcnt lgkmcnt(0)" ::: "memory"); \
                      __builtin_amdgcn_sched_barrier(0); } while (0)

// ---------------- LayerNorm (D=512), optional per-batch additive row, bf16 out ----
__global__ __launch_bounds__(256) void ln_k(
    const float* __restrict__ x, const float* __restrict__ add,
    const float* __restrict__ g, const float* __restrict__ bb,
    unsigned short* __restrict__ out)
{
  int row = blockIdx.x;
  int tid = threadIdx.x;
  const float* xr = x + (size_t)row * DIN;
  float v0 = xr[tid], v1 = xr[tid + 256];
  if (add) {
    const float* ar = add + (size_t)(row >> 10) * DIN;   // row/1024 = batch idx
    v0 += ar[tid]; v1 += ar[tid + 256];
  }
  float s = v0 + v1, sq = v0 * v0 + v1 * v1;
  #pragma unroll
  for (int m = 1; m < 64; m <<= 1) { s += __shfl_xor(s, m, 64); sq += __shfl_xor(sq, m, 64); }
  __shared__ float red[8];
  int w = tid >> 6;
  if ((tid & 63) == 0) { red[w] = s; red[4 + w] = sq; }
  __syncthreads();
  s  = red[0] + red[1] + red[2] + red[3];
  sq = red[4] + red[5] + red[6] + red[7];
  float mean = s * (1.0f / DIN);
  float var  = sq * (1.0f / DIN) - mean * mean;
  float rs = rsqrtf(var + 1e-5f);
  unsigned short* orow = out + (size_t)row * DIN;
  orow[tid]       = f2bf((v0 - mean) * rs * g[tid]       + bb[tid]);
  orow[tid + 256] = f2bf((v1 - mean) * rs * g[tid + 256] + bb[tid + 256]);
}

// ---------------- f32 [R][C] -> bf16 [C][R] transpose (weights) ------------------
__global__ __launch_bounds__(256) void wtrans_k(
    const float* __restrict__ in, unsigned short* __restrict__ out, int R, int C)
{
  __shared__ float tile[32][33];
  int tx = threadIdx.x & 31, ty = threadIdx.x >> 5;
  int c0 = blockIdx.x * 32, r0 = blockIdx.y * 32;
  #pragma unroll
  for (int k = 0; k < 4; ++k)
    tile[ty + k * 8][tx] = in[(size_t)(r0 + ty + k * 8) * C + c0 + tx];
  __syncthreads();
  #pragma unroll
  for (int k = 0; k < 4; ++k)
    out[(size_t)(c0 + ty + k * 8) * R + r0 + tx] = f2bf(tile[tx][ty + k * 8]);
}

// ---------------- time MLP: tp[b][512] = swish(t@Wt1+bt1)@Wt2+bt2 ---------------
__global__ __launch_bounds__(256) void time_k(
    const float* __restrict__ t, const float* __restrict__ Wt1, const float* __restrict__ bt1,
    const float* __restrict__ Wt2, const float* __restrict__ bt2, float* __restrict__ tp)
{
  int b = blockIdx.x, tid = threadIdx.x;
  __shared__ float tl[256], hl[256];
  tl[tid] = t[(size_t)b * 256 + tid];
  __syncthreads();
  float a = bt1[tid];
  for (int k = 0; k < 256; ++k) a += tl[k] * Wt1[(size_t)k * 256 + tid];
  hl[tid] = a / (1.0f + __expf(-a));
  __syncthreads();
  for (int j = tid; j < 512; j += 256) {
    float a2 = bt2[j];
    for (int k = 0; k < 256; ++k) a2 += hl[k] * Wt2[(size_t)k * 512 + j];
    tp[(size_t)b * 512 + j] = a2;
  }
}

// ---------------- bf16 MFMA GEMM: C = epi(A @ Bt^T + bias [+res]) ---------------
// 128x128 tile, BK=32, 4 waves; double-buffered LDS, 1 barrier/k-step (r9 config).
template<int EPI>
__global__ __launch_bounds__(256) void gemm_bt(
    const unsigned short* __restrict__ A, int lda,
    const unsigned short* __restrict__ Bt,
    const float* __restrict__ bias, const float* __restrict__ res,
    void* __restrict__ C, int ldc, int N, int K,
    unsigned short* __restrict__ vtout)
{
  __shared__ __attribute__((aligned(16))) unsigned short As[2 * 4096];
  __shared__ __attribute__((aligned(16))) unsigned short Bs[2 * 4096];
  int tid = threadIdx.x;
  int m0 = blockIdx.y * 128, n0 = blockIdx.x * 128;
  int lane = tid & 63, wid = tid >> 6;
  int wr = wid >> 1, wc = wid & 1;
  int lr = lane & 15, lg = lane >> 4, lk = lg * 8;
  f32x4 zero = {0.f, 0.f, 0.f, 0.f};
  f32x4 acc[4][4];
  #pragma unroll
  for (int i = 0; i < 4; ++i)
    #pragma unroll
    for (int j = 0; j < 4; ++j) acc[i][j] = zero;
  int srow = wid * 16 + (lane >> 2);
  int schunk = (lane & 3) * 8;
  const unsigned short* gA0 = A  + (size_t)(m0 + srow) * lda + schunk;
  const unsigned short* gA1 = gA0 + (size_t)64 * lda;
  const unsigned short* gB0 = Bt + (size_t)(n0 + srow) * K + schunk;
  const unsigned short* gB1 = gB0 + (size_t)64 * K;
  int nk = K >> 5;
  gload_lds16(gA0, As + wid * 512);
  gload_lds16(gA1, As + 2048 + wid * 512);
  gload_lds16(gB0, Bs + wid * 512);
  gload_lds16(gB1, Bs + 2048 + wid * 512);
  __syncthreads();
  for (int kq = 0; kq < nk; ++kq) {
    int cur = (kq & 1) * 4096;
    if (kq + 1 < nk) {
      int nxt = ((kq + 1) & 1) * 4096;
      int kt = (kq + 1) * 32;
      gload_lds16(gA0 + kt, As + nxt + wid * 512);
      gload_lds16(gA1 + kt, As + nxt + 2048 + wid * 512);
      gload_lds16(gB0 + kt, Bs + nxt + wid * 512);
      gload_lds16(gB1 + kt, Bs + nxt + 2048 + wid * 512);
    }
    s16x8 af[4], bf[4];
    #pragma unroll
    for (int mf = 0; mf < 4; ++mf)
      af[mf] = *(const s16x8*)&As[cur + (wr * 64 + mf * 16 + lr) * 32 + lk];
    #pragma unroll
    for (int nf = 0; nf < 4; ++nf)
      bf[nf] = *(const s16x8*)&Bs[cur + (wc * 64 + nf * 16 + lr) * 32 + lk];
    #pragma unroll
    for (int mf = 0; mf < 4; ++mf)
      #pragma unroll
      for (int nf = 0; nf < 4; ++nf)
        acc[mf][nf] = __builtin_amdgcn_mfma_f32_16x16x32_bf16(af[mf], bf[nf], acc[mf][nf], 0, 0, 0);
    __syncthreads();
  }
  if (EPI == 3 && n0 >= 2048) {
    #pragma unroll
    for (int mf = 0; mf < 4; ++mf) {
      int row = m0 + wr * 64 + mf * 16 + lg * 4;
      int bb = row >> 10, nn = row & 1023;
      #pragma unroll
      for (int nf = 0; nf < 4; ++nf) {
        int col = n0 + wc * 64 + nf * 16 + lr;
        float bcol = bias[col];
        int hc = col - 2048;
        int hh = hc >> 9, cc = hc & 511;
        unsigned short pk[4];
        #pragma unroll
        for (int r = 0; r < 4; ++r) pk[r] = f2bf(acc[mf][nf][r] + bcol);
        *(s16x4*)(vtout + ((size_t)((bb * 8 + hh) * 512 + cc)) * 1024 + nn) = *(const s16x4*)pk;
      }
    }
    return;
  }
  #pragma unroll
  for (int mf = 0; mf < 4; ++mf)
    #pragma unroll
    for (int nf = 0; nf < 4; ++nf) {
      int col = n0 + wc * 64 + nf * 16 + lr;
      float bcol = bias[col];
      #pragma unroll
      for (int r = 0; r < 4; ++r) {
        int row = m0 + wr * 64 + mf * 16 + lg * 4 + r;
        float v = acc[mf][nf][r] + bcol;
        if (EPI == 1) v = v / (1.0f + __expf(-v));            // swish
        if (EPI == 2) {
          v += res[(size_t)row * N + col];
          ((float*)C)[(size_t)row * ldc + col] = v;
        } else {
          ((unsigned short*)C)[(size_t)row * ldc + col] = f2bf(v);
        }
      }
    }
}

// ---------------- fused differential attention: SINGLE PASS, no-max softmax -----
// O1 = sum(e^{s1} V), O2 = sum(e^{s2} V), l1/l2 = row sums; out = O1/l1 - lam*O2/l2.
// No stats pass, no QK recompute; 32 iterations total (was 64).
// 8 waves: rs=w&3 (16-row q-stripe), kh=w>>2 (kv-16-half of each 32-kv tile).
// K: per-wave register prefetch (depth 1, counted vmcnt).
// V: wave-private LDS slices, triple-buffered global_load_lds (2-iter window).
// P1/P2: [64][36] dbuf each; ONE lgkm-only barrier per iteration.
__global__ __launch_bounds__(512) void attn_k(
    const unsigned short* __restrict__ qkv, const unsigned short* __restrict__ vt,
    const float* __restrict__ lamp, unsigned short* __restrict__ aout /* = qkv+2048 */)
{
  const float scale = 0.125f;
  __shared__ __attribute__((aligned(16))) unsigned short V3[3][512 * 32]; // 96KB
  __shared__ __attribute__((aligned(16))) unsigned short P1b[2][64 * 36]; // 9KB
  __shared__ __attribute__((aligned(16))) unsigned short P2b[2][64 * 36]; // 9KB
  __shared__ float sl[2][2][64];                                          // 1KB
  int w0 = blockIdx.x;
  int bx = (w0 & 7) * 128 + (w0 >> 3);        // 1024 blocks, bijective XCD swizzle
  int bh = bx >> 4, qt = bx & 15;
  int b = bh >> 3, h = bh & 7;
  int tid = threadIdx.x;
  int lane = tid & 63, w = tid >> 6;
  int rs = w & 3, kh = w >> 2;
  int lr = lane & 15, lg = lane >> 4, lk = lg * 8;
  int qc1 = h * 64, qc2 = 512 + h * 64, kc1 = 1024 + h * 64, kc2 = 1536 + h * 64;
  f32x4 zero = {0.f, 0.f, 0.f, 0.f};
  float lam = *lamp;

  // Q fragments (both types) for rows qt*64 + rs*16 + lr
  s16x8 q1f[2], q2f[2];
  {
    size_t ro = (size_t)(b * N_ + qt * 64 + rs * 16 + lr) * DQKV;
    q1f[0] = *(const s16x8*)(qkv + ro + qc1 + lk);
    q1f[1] = *(const s16x8*)(qkv + ro + qc1 + 32 + lk);
    q2f[0] = *(const s16x8*)(qkv + ro + qc2 + lk);
    q2f[1] = *(const s16x8*)(qkv + ro + qc2 + 32 + lk);
  }

  // V staging: wave-private slice [w*64 .. w*64+64) channels x 32 kv, linear dest;
  // source kv-chunk pre-swizzled: chunk = (lane&3) ^ ((lane>>3)&3)  (rule 21)
  auto stage_v = [&](unsigned short* buf, int kt) {
    int chnk = (lane & 3) ^ ((lane >> 3) & 3);
    #pragma unroll
    for (int i = 0; i < 4; ++i) {
      int ch = w * 64 + i * 16 + (lane >> 2);
      gload_lds16(vt + (size_t)(bh * 512 + ch) * N_ + kt * 32 + chnk * 8,
                  buf + (w * 64 + i * 16) * 32);
    }
  };
#define VREAD(vb, nf) \
  (*(const s16x8*)&(vb)[(w * 64 + (nf) * 16 + lr) * 32 + ((lg ^ ((lr >> 1) & 3)) * 8)])

  f32x4 O1[4][4], O2[4][4];
  #pragma unroll
  for (int mf = 0; mf < 4; ++mf)
    #pragma unroll
    for (int nf = 0; nf < 4; ++nf) { O1[mf][nf] = zero; O2[mf][nf] = zero; }
  float lp1[4] = {0.f, 0.f, 0.f, 0.f}, lp2[4] = {0.f, 0.f, 0.f, 0.f};

  // prologue: V(0), V(1) staged; K(0) regs
  stage_v(V3[0], 0);
  stage_v(V3[1], 1);
  s16x8 kcur[4], knxt[4];
  {
    size_t kro = (size_t)(b * N_ + kh * 16 + lr) * DQKV;
    kcur[0] = *(const s16x8*)(qkv + kro + kc1 + lk);
    kcur[1] = *(const s16x8*)(qkv + kro + kc1 + 32 + lk);
    kcur[2] = *(const s16x8*)(qkv + kro + kc2 + lk);
    kcur[3] = *(const s16x8*)(qkv + kro + kc2 + 32 + lk);
  }
  for (int kt = 0; kt < 32; ++kt) {
    // issue V(kt+2) then K(kt+1)  (drain order at the wait: ..V(kt+1),K(kt))
    if (kt + 2 < 32) stage_v(V3[(kt + 2) % 3], kt + 2);
    if (kt + 1 < 32) {
      size_t kro = (size_t)(b * N_ + (kt + 1) * 32 + kh * 16 + lr) * DQKV;
      knxt[0] = *(const s16x8*)(qkv + kro + kc1 + lk);
      knxt[1] = *(const s16x8*)(qkv + kro + kc1 + 32 + lk);
      knxt[2] = *(const s16x8*)(qkv + kro + kc2 + lk);
      knxt[3] = *(const s16x8*)(qkv + kro + kc2 + 32 + lk);
    }
    if (kt <= 29)      WAITV(8);   // drains K(kt) [+V(kt+1)]; keeps V(kt+2),K(kt+1)
    else if (kt == 30) WAITV(4);   // queue: V31,K30,K31 -> drains V31,K30
    else               WAITV(0);   // queue: K31 -> drain
    // QK both types, kv = kt*32 + kh*16 + lr
    f32x4 t1 = __builtin_amdgcn_mfma_f32_16x16x32_bf16(q1f[0], kcur[0], zero, 0, 0, 0);
    f32x4 s1 = __builtin_amdgcn_mfma_f32_16x16x32_bf16(q1f[1], kcur[1], t1, 0, 0, 0);
    f32x4 t2 = __builtin_amdgcn_mfma_f32_16x16x32_bf16(q2f[0], kcur[2], zero, 0, 0, 0);
    f32x4 s2 = __builtin_amdgcn_mfma_f32_16x16x32_bf16(q2f[1], kcur[3], t2, 0, 0, 0);
    // unnormalized P tiles (e^s bounded by e^4: bf16-safe); accumulate row sums
    unsigned short* P1t = P1b[kt & 1];
    unsigned short* P2t = P2b[kt & 1];
    #pragma unroll
    for (int r = 0; r < 4; ++r) {
      float e1 = __expf(s1[r] * scale);
      float e2 = __expf(s2[r] * scale);
      lp1[r] += e1; lp2[r] += e2;
      int off = (rs * 16 + lg * 4 + r) * 36 + kh * 16 + lr;
      P1t[off] = f2bf(e1);
      P2t[off] = f2bf(e2);
    }
    WAITL0();                          // P ds_writes visible; vmem stays in flight
    __builtin_amdgcn_s_barrier();      // ONE barrier per iteration
    // PV: P1,P2 [64][32] x wave's private V slice [32][64ch]
    __builtin_amdgcn_s_setprio(1);
    unsigned short* Vb = V3[kt % 3];
    #pragma unroll
    for (int mf = 0; mf < 4; ++mf) {
      s16x8 pf1 = *(const s16x8*)&P1t[(mf * 16 + lr) * 36 + lk];
      s16x8 pf2 = *(const s16x8*)&P2t[(mf * 16 + lr) * 36 + lk];
      #pragma unroll
      for (int nf = 0; nf < 4; ++nf) {
        s16x8 vfr = VREAD(Vb, nf);
        O1[mf][nf] = __builtin_amdgcn_mfma_f32_16x16x32_bf16(pf1, vfr, O1[mf][nf], 0, 0, 0);
        O2[mf][nf] = __builtin_amdgcn_mfma_f32_16x16x32_bf16(pf2, vfr, O2[mf][nf], 0, 0, 0);
      }
    }
    __builtin_amdgcn_s_setprio(0);
    if (kt < 31) {
      #pragma unroll
      for (int i = 0; i < 4; ++i) kcur[i] = knxt[i];
    }
  }
#undef VREAD
  // ---------------- epilogue: reduce l, normalize, write ------------------------
  #pragma unroll
  for (int r = 0; r < 4; ++r) {
    #pragma unroll
    for (int d = 1; d < 16; d <<= 1) {
      lp1[r] += __shfl_xor(lp1[r], d, 64);
      lp2[r] += __shfl_xor(lp2[r], d, 64);
    }
  }
  if (lr == 0) {
    #pragma unroll
    for (int r = 0; r < 4; ++r) {
      sl[0][kh][rs * 16 + lg * 4 + r] = lp1[r];
      sl[1][kh][rs * 16 + lg * 4 + r] = lp2[r];
    }
  }
  __syncthreads();
  #pragma unroll
  for (int mf = 0; mf < 4; ++mf) {
    float i1[4], i2[4];
    #pragma unroll
    for (int r = 0; r < 4; ++r) {
      int row = mf * 16 + lg * 4 + r;
      i1[r] = 1.0f / (sl[0][0][row] + sl[0][1][row]);
      i2[r] = lam  / (sl[1][0][row] + sl[1][1][row]);
    }
    #pragma unroll
    for (int nf = 0; nf < 4; ++nf) {
      int col = h * 512 + w * 64 + nf * 16 + lr;
      #pragma unroll
      for (int r = 0; r < 4; ++r) {
        int row = b * N_ + qt * 64 + mf * 16 + lg * 4 + r;
        aout[(size_t)row * DQKV + col] = f2bf(O1[mf][nf][r] * i1[r] - O2[mf][nf][r] * i2[r]);
      }
    }
  }
}

// ---------------------------------- launcher ------------------------------------
extern "C" void kernel_launch(void* const* d_in, const int* in_sizes, int n_in,
                              void* d_out, int out_size, void* d_ws, size_t ws_size,
                              hipStream_t stream) {
  const float* x    = (const float*)d_in[0];
  const float* t    = (const float*)d_in[1];
  const float* ln1g = (const float*)d_in[2];
  const float* ln1b = (const float*)d_in[3];
  const float* Wqkv = (const float*)d_in[4];
  const float* bqkv = (const float*)d_in[5];
  const float* lam  = (const float*)d_in[6];
  const float* Wm   = (const float*)d_in[7];
  const float* bm   = (const float*)d_in[8];
  const float* Wt1  = (const float*)d_in[9];
  const float* bt1  = (const float*)d_in[10];
  const float* Wt2  = (const float*)d_in[11];
  const float* bt2  = (const float*)d_in[12];
  const float* lnfg = (const float*)d_in[13];
  const float* lnfb = (const float*)d_in[14];
  const float* Wf1  = (const float*)d_in[15];
  const float* bf1  = (const float*)d_in[16];
  const float* Wf2  = (const float*)d_in[17];
  const float* bf2  = (const float*)d_in[18];
  float* out = (float*)d_out;
  char* ws = (char*)d_ws;

  // workspace layout (bytes), ~209 MB total
  unsigned short* qkv   = (unsigned short*)(ws);                  // [8192][6144] bf16 (100.7MB)
  unsigned short* vt    = (unsigned short*)(ws + 100663296ull);   // [64][512][1024] bf16 (67MB)
  float*          x2    = (float*)(ws + 167772160ull);            // [8192][512] f32 (16.8MB)
  unsigned short* xn    = (unsigned short*)(ws + 184549376ull);   // [8192][512] bf16 (xn, then h)
  unsigned short* WqkvT = (unsigned short*)(ws + 193986560ull);   // [6144][512]
  unsigned short* WmT   = (unsigned short*)(ws + 200278016ull);   // [512][4096]
  unsigned short* Wf1T  = (unsigned short*)(ws + 204472320ull);   // [2048][512]
  unsigned short* Wf2T  = (unsigned short*)(ws + 206569472ull);   // [512][2048]
  float*          tp    = (float*)(ws + 208666624ull);            // [8][512]
  unsigned short* ff1s  = qkv;          // alias: qkv dead after attention
  unsigned short* aout  = qkv + 2048;   // alias: attention out over dead V region

  // weights -> bf16 transposed [N][K]
  wtrans_k<<<dim3(DQKV / 32, DIN / 32),  256, 0, stream>>>(Wqkv, WqkvT, DIN, DQKV);
  wtrans_k<<<dim3(DIN / 32, 4096 / 32),  256, 0, stream>>>(Wm,   WmT,   4096, DIN);
  wtrans_k<<<dim3(DEXP / 32, DIN / 32),  256, 0, stream>>>(Wf1,  Wf1T,  DIN, DEXP);
  wtrans_k<<<dim3(DIN / 32, DEXP / 32),  256, 0, stream>>>(Wf2,  Wf2T,  DEXP, DIN);
  // ln1 + time MLP
  ln_k<<<8192, 256, 0, stream>>>(x, nullptr, ln1g, ln1b, xn);
  time_k<<<8, 256, 0, stream>>>(t, Wt1, bt1, Wt2, bt2, tp);
  // qkv GEMM (V columns written directly transposed into vt)
  gemm_bt<3><<<dim3(DQKV / 128, 8192 / 128), 256, 0, stream>>>(
      xn, DIN, WqkvT, bqkv, nullptr, qkv, DQKV, DQKV, DIN, vt);
  // fused single-pass differential attention
  attn_k<<<1024, 512, 0, stream>>>(qkv, vt, lam, aout);
  // x2 = x + attn_out @ Wm + bm
  gemm_bt<2><<<dim3(DIN / 128, 8192 / 128), 256, 0, stream>>>(
      aout, DQKV, WmT, bm, x, x2, DIN, DIN, 4096, nullptr);
  // h = LN(x2 + tp)
  ln_k<<<8192, 256, 0, stream>>>(x2, tp, lnfg, lnfb, xn);
  // ff1 = swish(h @ Wf1 + bf1)
  gemm_bt<1><<<dim3(DEXP / 128, 8192 / 128), 256, 0, stream>>>(
      xn, DIN, Wf1T, bf1, nullptr, ff1s, DEXP, DEXP, DIN, nullptr);
  // out = x2 + ff1 @ Wf2 + bf2
  gemm_bt<2><<<dim3(DIN / 128, 8192 / 128), 256, 0, stream>>>(
      ff1s, DEXP, Wf2T, bf2, x2, out, DIN, DIN, DEXP, nullptr);
}

// Round 15
// 591.076 us; speedup vs baseline: 1.1604x; 1.1604x over previous
//
#include <hip/hip_runtime.h>

// Problem dims
#define B_    8
#define N_    1024
#define DIN   512
#define H_    8
#define DH    64
#define DQKV  6144   // 2*DQ + 2*DQ + DV = 512+512+512+512+4096
#define DEXP  2048
#define DTIME 256

typedef __attribute__((ext_vector_type(8))) short s16x8;   // 8 bf16 (MFMA A/B frag)
typedef __attribute__((ext_vector_type(4))) short s16x4;
typedef __attribute__((ext_vector_type(4))) float f32x4;   // MFMA C/D frag

__device__ __forceinline__ unsigned short f2bf(float f) {
  unsigned int u = __float_as_uint(f);
  u = (u + 0x7fffu + ((u >> 16) & 1u)) >> 16;   // RNE
  return (unsigned short)u;
}

__device__ __forceinline__ void gload_lds16(const unsigned short* g, unsigned short* l) {
  __builtin_amdgcn_global_load_lds(
      (const __attribute__((address_space(1))) unsigned int*)(g),
      (__attribute__((address_space(3))) unsigned int*)(l), 16, 0, 0);
}

// ---------------- LayerNorm (D=512), optional per-batch additive row, bf16 out ----
__global__ __launch_bounds__(256) void ln_k(
    const float* __restrict__ x, const float* __restrict__ add,
    const float* __restrict__ g, const float* __restrict__ bb,
    unsigned short* __restrict__ out)
{
  int row = blockIdx.x;
  int tid = threadIdx.x;
  const float* xr = x + (size_t)row * DIN;
  float v0 = xr[tid], v1 = xr[tid + 256];
  if (add) {
    const float* ar = add + (size_t)(row >> 10) * DIN;   // row/1024 = batch idx
    v0 += ar[tid]; v1 += ar[tid + 256];
  }
  float s = v0 + v1, sq = v0 * v0 + v1 * v1;
  #pragma unroll
  for (int m = 1; m < 64; m <<= 1) { s += __shfl_xor(s, m, 64); sq += __shfl_xor(sq, m, 64); }
  __shared__ float red[8];
  int w = tid >> 6;
  if ((tid & 63) == 0) { red[w] = s; red[4 + w] = sq; }
  __syncthreads();
  s  = red[0] + red[1] + red[2] + red[3];
  sq = red[4] + red[5] + red[6] + red[7];
  float mean = s * (1.0f / DIN);
  float var  = sq * (1.0f / DIN) - mean * mean;
  float rs = rsqrtf(var + 1e-5f);
  unsigned short* orow = out + (size_t)row * DIN;
  orow[tid]       = f2bf((v0 - mean) * rs * g[tid]       + bb[tid]);
  orow[tid + 256] = f2bf((v1 - mean) * rs * g[tid + 256] + bb[tid + 256]);
}

// ---------------- f32 [R][C] -> bf16 [C][R] transpose (weights) ------------------
__global__ __launch_bounds__(256) void wtrans_k(
    const float* __restrict__ in, unsigned short* __restrict__ out, int R, int C)
{
  __shared__ float tile[32][33];
  int tx = threadIdx.x & 31, ty = threadIdx.x >> 5;
  int c0 = blockIdx.x * 32, r0 = blockIdx.y * 32;
  #pragma unroll
  for (int k = 0; k < 4; ++k)
    tile[ty + k * 8][tx] = in[(size_t)(r0 + ty + k * 8) * C + c0 + tx];
  __syncthreads();
  #pragma unroll
  for (int k = 0; k < 4; ++k)
    out[(size_t)(c0 + ty + k * 8) * R + r0 + tx] = f2bf(tile[tx][ty + k * 8]);
}

// ---------------- time MLP: tp[b][512] = swish(t@Wt1+bt1)@Wt2+bt2 ---------------
__global__ __launch_bounds__(256) void time_k(
    const float* __restrict__ t, const float* __restrict__ Wt1, const float* __restrict__ bt1,
    const float* __restrict__ Wt2, const float* __restrict__ bt2, float* __restrict__ tp)
{
  int b = blockIdx.x, tid = threadIdx.x;
  __shared__ float tl[256], hl[256];
  tl[tid] = t[(size_t)b * 256 + tid];
  __syncthreads();
  float a = bt1[tid];
  for (int k = 0; k < 256; ++k) a += tl[k] * Wt1[(size_t)k * 256 + tid];
  hl[tid] = a / (1.0f + __expf(-a));
  __syncthreads();
  for (int j = tid; j < 512; j += 256) {
    float a2 = bt2[j];
    for (int k = 0; k < 256; ++k) a2 += hl[k] * Wt2[(size_t)k * 512 + j];
    tp[(size_t)b * 512 + j] = a2;
  }
}

// ---------------- bf16 MFMA GEMM: C = epi(A @ Bt^T + bias [+res]) ---------------
// 128x128 tile, BK=64, 4 waves; double-buffered LDS, 1 barrier/k-step.
// 32 MFMA per barrier (2x the BK=32 version). LDS rows are 128B -> XOR-swizzle
// (rule 21): linear dest, source chunk (lane&7)^(lane>>3), read colu^((row&7)*8).
template<int EPI>
__global__ __launch_bounds__(256) void gemm_bt(
    const unsigned short* __restrict__ A, int lda,
    const unsigned short* __restrict__ Bt,
    const float* __restrict__ bias, const float* __restrict__ res,
    void* __restrict__ C, int ldc, int N, int K,
    unsigned short* __restrict__ vtout)
{
  __shared__ __attribute__((aligned(16))) unsigned short As[2 * 8192]; // 128x64 x2
  __shared__ __attribute__((aligned(16))) unsigned short Bs[2 * 8192];
  int tid = threadIdx.x;
  int m0 = blockIdx.y * 128, n0 = blockIdx.x * 128;
  int lane = tid & 63, wid = tid >> 6;
  int wr = wid >> 1, wc = wid & 1;
  int lr = lane & 15, lg = lane >> 4, lk = lg * 8;
  f32x4 zero = {0.f, 0.f, 0.f, 0.f};
  f32x4 acc[4][4];
  #pragma unroll
  for (int i = 0; i < 4; ++i)
    #pragma unroll
    for (int j = 0; j < 4; ++j) acc[i][j] = zero;
  // staging: instr i covers rows i*32 + wid*8 + (lane>>3); src col pre-swizzled
  int srow = wid * 8 + (lane >> 3);
  int scol = ((lane & 7) ^ (lane >> 3)) * 8;
  const unsigned short* gA = A  + (size_t)(m0 + srow) * lda + scol;
  const unsigned short* gB = Bt + (size_t)(n0 + srow) * K + scol;
  int nk = K >> 6;
  #pragma unroll
  for (int i = 0; i < 4; ++i) {
    gload_lds16(gA + (size_t)(i * 32) * lda, As + (i * 32 + wid * 8) * 64);
    gload_lds16(gB + (size_t)(i * 32) * K,   Bs + (i * 32 + wid * 8) * 64);
  }
  __syncthreads();
#define GSWZ(Lb, base, row, colu) \
  (*(const s16x8*)&(Lb)[(base) + (row) * 64 + (((colu) ^ (((row) & 7) * 8)))])
  for (int kq = 0; kq < nk; ++kq) {
    int cur = (kq & 1) * 8192;
    if (kq + 1 < nk) {
      int nxt = ((kq + 1) & 1) * 8192;
      int kt = (kq + 1) * 64;
      #pragma unroll
      for (int i = 0; i < 4; ++i) {
        gload_lds16(gA + (size_t)(i * 32) * lda + kt, As + nxt + (i * 32 + wid * 8) * 64);
        gload_lds16(gB + (size_t)(i * 32) * K   + kt, Bs + nxt + (i * 32 + wid * 8) * 64);
      }
    }
    s16x8 af[4][2], bf[4][2];
    #pragma unroll
    for (int mf = 0; mf < 4; ++mf) {
      int row = wr * 64 + mf * 16 + lr;
      af[mf][0] = GSWZ(As, cur, row, lk);
      af[mf][1] = GSWZ(As, cur, row, 32 + lk);
    }
    #pragma unroll
    for (int nf = 0; nf < 4; ++nf) {
      int row = wc * 64 + nf * 16 + lr;
      bf[nf][0] = GSWZ(Bs, cur, row, lk);
      bf[nf][1] = GSWZ(Bs, cur, row, 32 + lk);
    }
    #pragma unroll
    for (int mf = 0; mf < 4; ++mf)
      #pragma unroll
      for (int nf = 0; nf < 4; ++nf) {
        acc[mf][nf] = __builtin_amdgcn_mfma_f32_16x16x32_bf16(af[mf][0], bf[nf][0], acc[mf][nf], 0, 0, 0);
        acc[mf][nf] = __builtin_amdgcn_mfma_f32_16x16x32_bf16(af[mf][1], bf[nf][1], acc[mf][nf], 0, 0, 0);
      }
    __syncthreads();
  }
#undef GSWZ
  if (EPI == 3 && n0 >= 2048) {
    #pragma unroll
    for (int mf = 0; mf < 4; ++mf) {
      int row = m0 + wr * 64 + mf * 16 + lg * 4;
      int bb = row >> 10, nn = row & 1023;
      #pragma unroll
      for (int nf = 0; nf < 4; ++nf) {
        int col = n0 + wc * 64 + nf * 16 + lr;
        float bcol = bias[col];
        int hc = col - 2048;
        int hh = hc >> 9, cc = hc & 511;
        unsigned short pk[4];
        #pragma unroll
        for (int r = 0; r < 4; ++r) pk[r] = f2bf(acc[mf][nf][r] + bcol);
        *(s16x4*)(vtout + ((size_t)((bb * 8 + hh) * 512 + cc)) * 1024 + nn) = *(const s16x4*)pk;
      }
    }
    return;
  }
  #pragma unroll
  for (int mf = 0; mf < 4; ++mf)
    #pragma unroll
    for (int nf = 0; nf < 4; ++nf) {
      int col = n0 + wc * 64 + nf * 16 + lr;
      float bcol = bias[col];
      #pragma unroll
      for (int r = 0; r < 4; ++r) {
        int row = m0 + wr * 64 + mf * 16 + lg * 4 + r;
        float v = acc[mf][nf][r] + bcol;
        if (EPI == 1) v = v / (1.0f + __expf(-v));            // swish
        if (EPI == 2) {
          v += res[(size_t)row * N + col];
          ((float*)C)[(size_t)row * ldc + col] = v;
        } else {
          ((unsigned short*)C)[(size_t)row * ldc + col] = f2bf(v);
        }
      }
    }
}

// ---------------- fused differential attention (r7-exact, measured best) --------
// QBLK=64, LDS-staged K (XOR-swizzled), no-max softmax, two-pass exact.
__global__ __launch_bounds__(512) void attn_k(
    const unsigned short* __restrict__ qkv, const unsigned short* __restrict__ vt,
    const float* __restrict__ lamp, unsigned short* __restrict__ aout /* = qkv+2048 */)
{
  const float scale = 0.125f;
  __shared__ __attribute__((aligned(16))) unsigned short KP[16896];
  __shared__ float sl[2][64];
  int w0 = blockIdx.x;
  int bx = (w0 & 7) * 128 + (w0 >> 3);        // 1024 blocks, bijective XCD swizzle
  int bh = bx >> 4, qt = bx & 15;
  int b = bh >> 3, h = bh & 7;
  int tid = threadIdx.x;
  int lane = tid & 63, w = tid >> 6;
  int rs = w & 3, kh = w >> 2;
  int lr = lane & 15, lg = lane >> 4, lk = lg * 8;
  int qc1 = h * 64, qc2 = 512 + h * 64, kc1 = 1024 + h * 64, kc2 = 1536 + h * 64;
  f32x4 zero = {0.f, 0.f, 0.f, 0.f};
  const unsigned short* kvbase = qkv + (size_t)(b * N_) * DQKV;

  int srw = lane >> 4;                        // 0..3
  int ci0 = (lane & 15) ^ srw;
  int ci1 = (lane & 15) ^ (4 + srw);
  int scol0 = (ci0 < 8) ? (kc1 + ci0 * 8) : (kc2 + (ci0 - 8) * 8);
  int scol1 = (ci1 < 8) ? (kc1 + ci1 * 8) : (kc2 + (ci1 - 8) * 8);

  s16x8 q1f[2], q2f[2];
  {
    size_t ro = (size_t)(b * N_ + qt * 64 + rs * 16 + lr) * DQKV;
    q1f[0] = *(const s16x8*)(qkv + ro + qc1 + lk);
    q1f[1] = *(const s16x8*)(qkv + ro + qc1 + 32 + lk);
    q2f[0] = *(const s16x8*)(qkv + ro + qc2 + lk);
    q2f[1] = *(const s16x8*)(qkv + ro + qc2 + 32 + lk);
  }

#define STAGE_K(Lb, kt)                                                              \
  do {                                                                               \
    gload_lds16(kvbase + (size_t)((kt) * 64 + w * 8 + srw) * DQKV + scol0,           \
                (Lb) + (w * 8) * 128);                                               \
    gload_lds16(kvbase + (size_t)((kt) * 64 + w * 8 + 4 + srw) * DQKV + scol1,       \
                (Lb) + (w * 8 + 4) * 128);                                           \
  } while (0)

#define KREAD(Lb, row, colu) (*(const s16x8*)&(Lb)[(row) * 128 + ((colu) ^ (((row) & 7) * 8))])

  // ---------------- pass 1: l (sum of exp) for (rows rs*16.., type kh) ----------
  {
    unsigned short* K0 = KP;
    unsigned short* K1 = KP + 8192;
    s16x8 qa = kh ? q2f[0] : q1f[0];
    s16x8 qb = kh ? q2f[1] : q1f[1];
    int tco = kh ? 64 : 0;
    float lp[4] = {0.f, 0.f, 0.f, 0.f};
    STAGE_K(K0, 0);
    __syncthreads();
    for (int kt = 0; kt < 16; ++kt) {
      unsigned short* Lb = (kt & 1) ? K1 : K0;
      if (kt < 15) STAGE_K((kt & 1) ? K0 : K1, kt + 1);   // other buffer: race-free
      f32x4 s[4];
      #pragma unroll
      for (int nf = 0; nf < 4; ++nf) {
        int row = nf * 16 + lr;
        s16x8 kb0 = KREAD(Lb, row, tco + lk);
        s16x8 kb1 = KREAD(Lb, row, tco + 32 + lk);
        f32x4 acc = __builtin_amdgcn_mfma_f32_16x16x32_bf16(qa, kb0, zero, 0, 0, 0);
        s[nf] = __builtin_amdgcn_mfma_f32_16x16x32_bf16(qb, kb1, acc, 0, 0, 0);
      }
      #pragma unroll
      for (int nf = 0; nf < 4; ++nf)
        #pragma unroll
        for (int r = 0; r < 4; ++r)
          lp[r] += __expf(s[nf][r] * scale);
      __syncthreads();                 // next-tile stage drained; all reads done
    }
    #pragma unroll
    for (int r = 0; r < 4; ++r)
      #pragma unroll
      for (int d = 1; d < 16; d <<= 1) lp[r] += __shfl_xor(lp[r], d, 64);
    if (lr == 0)
      #pragma unroll
      for (int r = 0; r < 4; ++r) sl[kh][rs * 16 + lg * 4 + r] = lp[r];
    __syncthreads();
  }

  // normalizers for this lane's q-rows
  float lam = *lamp;
  float r1v[4], r2v[4];
  #pragma unroll
  for (int r = 0; r < 4; ++r) {
    int row = rs * 16 + lg * 4 + r;
    r1v[r] = 1.f / sl[0][row];
    r2v[r] = lam / sl[1][row];
  }

  // ---------------- pass 2: P tiles + PV ---------------------------------------
  unsigned short* Ks = KP;
  unsigned short* Pb = KP + 8192;
  f32x4 O[4][4];
  #pragma unroll
  for (int mf = 0; mf < 4; ++mf)
    #pragma unroll
    for (int nf = 0; nf < 4; ++nf) O[mf][nf] = zero;
  STAGE_K(Ks, 0);
  __syncthreads();
  for (int kt = 0; kt < 16; ++kt) {
    unsigned short* Pt = Pb + (kt & 1) * 4352;     // [64][68] halves
    // QK both types, kv rows kh*32 + nf*16 + lr (bit-identical order to pass 1)
    f32x4 s1[2], s2[2];
    #pragma unroll
    for (int nf = 0; nf < 2; ++nf) {
      int row = kh * 32 + nf * 16 + lr;
      s16x8 a0 = KREAD(Ks, row, lk);
      s16x8 a1 = KREAD(Ks, row, 32 + lk);
      s16x8 b0 = KREAD(Ks, row, 64 + lk);
      s16x8 b1 = KREAD(Ks, row, 96 + lk);
      f32x4 t1 = __builtin_amdgcn_mfma_f32_16x16x32_bf16(q1f[0], a0, zero, 0, 0, 0);
      s1[nf]   = __builtin_amdgcn_mfma_f32_16x16x32_bf16(q1f[1], a1, t1, 0, 0, 0);
      f32x4 t2 = __builtin_amdgcn_mfma_f32_16x16x32_bf16(q2f[0], b0, zero, 0, 0, 0);
      s2[nf]   = __builtin_amdgcn_mfma_f32_16x16x32_bf16(q2f[1], b1, t2, 0, 0, 0);
    }
    // V prefetch: issued before the barrier, drained by it -> ready for PV
    s16x8 vf[4][2];
    #pragma unroll
    for (int nf = 0; nf < 4; ++nf)
      #pragma unroll
      for (int kq = 0; kq < 2; ++kq)
        vf[nf][kq] = *(const s16x8*)(vt + (size_t)(bh * 512 + w * 64 + nf * 16 + lr) * N_
                                     + kt * 64 + kq * 32 + lk);
    // P = e1/l1 - lam*e2/l2 (no-max exact softmax), write stripe
    #pragma unroll
    for (int nf = 0; nf < 2; ++nf)
      #pragma unroll
      for (int r = 0; r < 4; ++r) {
        float p = __expf(s1[nf][r] * scale) * r1v[r]
                - __expf(s2[nf][r] * scale) * r2v[r];
        Pt[(rs * 16 + lg * 4 + r) * 68 + kh * 32 + nf * 16 + lr] = f2bf(p);
      }
    __syncthreads();                   // P ready; K consumed by all; vf landed
    if (kt < 15) STAGE_K(Ks, kt + 1);  // safe: all K reads done; drains under PV
    // PV: full P tile [64][64] x wave's 64 v-channels
    #pragma unroll
    for (int mf = 0; mf < 4; ++mf) {
      s16x8 pf0 = *(const s16x8*)&Pt[(mf * 16 + lr) * 68 + lk];
      s16x8 pf1 = *(const s16x8*)&Pt[(mf * 16 + lr) * 68 + 32 + lk];
      #pragma unroll
      for (int nf = 0; nf < 4; ++nf) {
        O[mf][nf] = __builtin_amdgcn_mfma_f32_16x16x32_bf16(pf0, vf[nf][0], O[mf][nf], 0, 0, 0);
        O[mf][nf] = __builtin_amdgcn_mfma_f32_16x16x32_bf16(pf1, vf[nf][1], O[mf][nf], 0, 0, 0);
      }
    }
    __syncthreads();                   // stage(kt+1) drained; P reads done
  }
#undef STAGE_K
#undef KREAD
  // epilogue
  #pragma unroll
  for (int mf = 0; mf < 4; ++mf)
    #pragma unroll
    for (int nf = 0; nf < 4; ++nf) {
      int col = h * 512 + w * 64 + nf * 16 + lr;
      #pragma unroll
      for (int r = 0; r < 4; ++r) {
        int row = b * N_ + qt * 64 + mf * 16 + lg * 4 + r;
        aout[(size_t)row * DQKV + col] = f2bf(O[mf][nf][r]);
      }
    }
}

// ---------------------------------- launcher ------------------------------------
extern "C" void kernel_launch(void* const* d_in, const int* in_sizes, int n_in,
                              void* d_out, int out_size, void* d_ws, size_t ws_size,
                              hipStream_t stream) {
  const float* x    = (const float*)d_in[0];
  const float* t    = (const float*)d_in[1];
  const float* ln1g = (const float*)d_in[2];
  const float* ln1b = (const float*)d_in[3];
  const float* Wqkv = (const float*)d_in[4];
  const float* bqkv = (const float*)d_in[5];
  const float* lam  = (const float*)d_in[6];
  const float* Wm   = (const float*)d_in[7];
  const float* bm   = (const float*)d_in[8];
  const float* Wt1  = (const float*)d_in[9];
  const float* bt1  = (const float*)d_in[10];
  const float* Wt2  = (const float*)d_in[11];
  const float* bt2  = (const float*)d_in[12];
  const float* lnfg = (const float*)d_in[13];
  const float* lnfb = (const float*)d_in[14];
  const float* Wf1  = (const float*)d_in[15];
  const float* bf1  = (const float*)d_in[16];
  const float* Wf2  = (const float*)d_in[17];
  const float* bf2  = (const float*)d_in[18];
  float* out = (float*)d_out;
  char* ws = (char*)d_ws;

  // workspace layout (bytes), ~209 MB total
  unsigned short* qkv   = (unsigned short*)(ws);                  // [8192][6144] bf16 (100.7MB)
  unsigned short* vt    = (unsigned short*)(ws + 100663296ull);   // [64][512][1024] bf16 (67MB)
  float*          x2    = (float*)(ws + 167772160ull);            // [8192][512] f32 (16.8MB)
  unsigned short* xn    = (unsigned short*)(ws + 184549376ull);   // [8192][512] bf16 (xn, then h)
  unsigned short* WqkvT = (unsigned short*)(ws + 193986560ull);   // [6144][512]
  unsigned short* WmT   = (unsigned short*)(ws + 200278016ull);   // [512][4096]
  unsigned short* Wf1T  = (unsigned short*)(ws + 204472320ull);   // [2048][512]
  unsigned short* Wf2T  = (unsigned short*)(ws + 206569472ull);   // [512][2048]
  float*          tp    = (float*)(ws + 208666624ull);            // [8][512]
  unsigned short* ff1s  = qkv;          // alias: qkv dead after attention
  unsigned short* aout  = qkv + 2048;   // alias: attention out over dead V region

  // weights -> bf16 transposed [N][K]
  wtrans_k<<<dim3(DQKV / 32, DIN / 32),  256, 0, stream>>>(Wqkv, WqkvT, DIN, DQKV);
  wtrans_k<<<dim3(DIN / 32, 4096 / 32),  256, 0, stream>>>(Wm,   WmT,   4096, DIN);
  wtrans_k<<<dim3(DEXP / 32, DIN / 32),  256, 0, stream>>>(Wf1,  Wf1T,  DIN, DEXP);
  wtrans_k<<<dim3(DIN / 32, DEXP / 32),  256, 0, stream>>>(Wf2,  Wf2T,  DEXP, DIN);
  // ln1 + time MLP
  ln_k<<<8192, 256, 0, stream>>>(x, nullptr, ln1g, ln1b, xn);
  time_k<<<8, 256, 0, stream>>>(t, Wt1, bt1, Wt2, bt2, tp);
  // qkv GEMM (V columns written directly transposed into vt)
  gemm_bt<3><<<dim3(DQKV / 128, 8192 / 128), 256, 0, stream>>>(
      xn, DIN, WqkvT, bqkv, nullptr, qkv, DQKV, DQKV, DIN, vt);
  // fused two-pass differential attention (r7-exact)
  attn_k<<<1024, 512, 0, stream>>>(qkv, vt, lam, aout);
  // x2 = x + attn_out @ Wm + bm
  gemm_bt<2><<<dim3(DIN / 128, 8192 / 128), 256, 0, stream>>>(
      aout, DQKV, WmT, bm, x, x2, DIN, DIN, 4096, nullptr);
  // h = LN(x2 + tp)
  ln_k<<<8192, 256, 0, stream>>>(x2, tp, lnfg, lnfb, xn);
  // ff1 = swish(h @ Wf1 + bf1)
  gemm_bt<1><<<dim3(DEXP / 128, 8192 / 128), 256, 0, stream>>>(
      xn, DIN, Wf1T, bf1, nullptr, ff1s, DEXP, DEXP, DIN, nullptr);
  // out = x2 + ff1 @ Wf2 + bf2
  gemm_bt<2><<<dim3(DIN / 128, 8192 / 128), 256, 0, stream>>>(
      ff1s, DEXP, Wf2T, bf2, x2, out, DIN, DIN, DEXP, nullptr);
}

// Round 16
// 507.876 us; speedup vs baseline: 1.3505x; 1.1638x over previous
//
#include <hip/hip_runtime.h>

// Problem dims
#define B_    8
#define N_    1024
#define DIN   512
#define H_    8
#define DH    64
#define DQKV  6144   // 2*DQ + 2*DQ + DV = 512+512+512+512+4096
#define DEXP  2048
#define DTIME 256

typedef __attribute__((ext_vector_type(8))) short s16x8;   // 8 bf16 (MFMA A/B frag)
typedef __attribute__((ext_vector_type(4))) short s16x4;
typedef __attribute__((ext_vector_type(4))) float f32x4;   // MFMA C/D frag

__device__ __forceinline__ unsigned short f2bf(float f) {
  unsigned int u = __float_as_uint(f);
  u = (u + 0x7fffu + ((u >> 16) & 1u)) >> 16;   // RNE
  return (unsigned short)u;
}

__device__ __forceinline__ void gload_lds16(const unsigned short* g, unsigned short* l) {
  __builtin_amdgcn_global_load_lds(
      (const __attribute__((address_space(1))) unsigned int*)(g),
      (__attribute__((address_space(3))) unsigned int*)(l), 16, 0, 0);
}

// ---------------- LayerNorm (D=512), optional per-batch additive row, bf16 out ----
__global__ __launch_bounds__(256) void ln_k(
    const float* __restrict__ x, const float* __restrict__ add,
    const float* __restrict__ g, const float* __restrict__ bb,
    unsigned short* __restrict__ out)
{
  int row = blockIdx.x;
  int tid = threadIdx.x;
  const float* xr = x + (size_t)row * DIN;
  float v0 = xr[tid], v1 = xr[tid + 256];
  if (add) {
    const float* ar = add + (size_t)(row >> 10) * DIN;   // row/1024 = batch idx
    v0 += ar[tid]; v1 += ar[tid + 256];
  }
  float s = v0 + v1, sq = v0 * v0 + v1 * v1;
  #pragma unroll
  for (int m = 1; m < 64; m <<= 1) { s += __shfl_xor(s, m, 64); sq += __shfl_xor(sq, m, 64); }
  __shared__ float red[8];
  int w = tid >> 6;
  if ((tid & 63) == 0) { red[w] = s; red[4 + w] = sq; }
  __syncthreads();
  s  = red[0] + red[1] + red[2] + red[3];
  sq = red[4] + red[5] + red[6] + red[7];
  float mean = s * (1.0f / DIN);
  float var  = sq * (1.0f / DIN) - mean * mean;
  float rs = rsqrtf(var + 1e-5f);
  unsigned short* orow = out + (size_t)row * DIN;
  orow[tid]       = f2bf((v0 - mean) * rs * g[tid]       + bb[tid]);
  orow[tid + 256] = f2bf((v1 - mean) * rs * g[tid + 256] + bb[tid + 256]);
}

// ---------------- f32 [R][C] -> bf16 [C][R] transpose (weights) ------------------
__global__ __launch_bounds__(256) void wtrans_k(
    const float* __restrict__ in, unsigned short* __restrict__ out, int R, int C)
{
  __shared__ float tile[32][33];
  int tx = threadIdx.x & 31, ty = threadIdx.x >> 5;
  int c0 = blockIdx.x * 32, r0 = blockIdx.y * 32;
  #pragma unroll
  for (int k = 0; k < 4; ++k)
    tile[ty + k * 8][tx] = in[(size_t)(r0 + ty + k * 8) * C + c0 + tx];
  __syncthreads();
  #pragma unroll
  for (int k = 0; k < 4; ++k)
    out[(size_t)(c0 + ty + k * 8) * R + r0 + tx] = f2bf(tile[tx][ty + k * 8]);
}

// ---------------- time MLP: tp[b][512] = swish(t@Wt1+bt1)@Wt2+bt2 ---------------
__global__ __launch_bounds__(256) void time_k(
    const float* __restrict__ t, const float* __restrict__ Wt1, const float* __restrict__ bt1,
    const float* __restrict__ Wt2, const float* __restrict__ bt2, float* __restrict__ tp)
{
  int b = blockIdx.x, tid = threadIdx.x;
  __shared__ float tl[256], hl[256];
  tl[tid] = t[(size_t)b * 256 + tid];
  __syncthreads();
  float a = bt1[tid];
  for (int k = 0; k < 256; ++k) a += tl[k] * Wt1[(size_t)k * 256 + tid];
  hl[tid] = a / (1.0f + __expf(-a));
  __syncthreads();
  for (int j = tid; j < 512; j += 256) {
    float a2 = bt2[j];
    for (int k = 0; k < 256; ++k) a2 += hl[k] * Wt2[(size_t)k * 512 + j];
    tp[(size_t)b * 512 + j] = a2;
  }
}

// ---------------- bf16 MFMA GEMM: C = epi(A @ Bt^T + bias [+res]) ---------------
// 128x128 tile, BK=64, 4 waves; double-buffered LDS, 1 barrier/k-step.
// 32 MFMA per barrier. XOR-swizzle (rule 21): linear dest, pre-swizzled source,
// read colu^((row&7)*8).
template<int EPI>
__global__ __launch_bounds__(256) void gemm_bt(
    const unsigned short* __restrict__ A, int lda,
    const unsigned short* __restrict__ Bt,
    const float* __restrict__ bias, const float* __restrict__ res,
    void* __restrict__ C, int ldc, int N, int K,
    unsigned short* __restrict__ vtout)
{
  __shared__ __attribute__((aligned(16))) unsigned short As[2 * 8192]; // 128x64 x2
  __shared__ __attribute__((aligned(16))) unsigned short Bs[2 * 8192];
  int tid = threadIdx.x;
  int m0 = blockIdx.y * 128, n0 = blockIdx.x * 128;
  int lane = tid & 63, wid = tid >> 6;
  int wr = wid >> 1, wc = wid & 1;
  int lr = lane & 15, lg = lane >> 4, lk = lg * 8;
  f32x4 zero = {0.f, 0.f, 0.f, 0.f};
  f32x4 acc[4][4];
  #pragma unroll
  for (int i = 0; i < 4; ++i)
    #pragma unroll
    for (int j = 0; j < 4; ++j) acc[i][j] = zero;
  // staging: instr i covers rows i*32 + wid*8 + (lane>>3); src col pre-swizzled
  int srow = wid * 8 + (lane >> 3);
  int scol = ((lane & 7) ^ (lane >> 3)) * 8;
  const unsigned short* gA = A  + (size_t)(m0 + srow) * lda + scol;
  const unsigned short* gB = Bt + (size_t)(n0 + srow) * K + scol;
  int nk = K >> 6;
  #pragma unroll
  for (int i = 0; i < 4; ++i) {
    gload_lds16(gA + (size_t)(i * 32) * lda, As + (i * 32 + wid * 8) * 64);
    gload_lds16(gB + (size_t)(i * 32) * K,   Bs + (i * 32 + wid * 8) * 64);
  }
  __syncthreads();
#define GSWZ(Lb, base, row, colu) \
  (*(const s16x8*)&(Lb)[(base) + (row) * 64 + (((colu) ^ (((row) & 7) * 8)))])
  for (int kq = 0; kq < nk; ++kq) {
    int cur = (kq & 1) * 8192;
    if (kq + 1 < nk) {
      int nxt = ((kq + 1) & 1) * 8192;
      int kt = (kq + 1) * 64;
      #pragma unroll
      for (int i = 0; i < 4; ++i) {
        gload_lds16(gA + (size_t)(i * 32) * lda + kt, As + nxt + (i * 32 + wid * 8) * 64);
        gload_lds16(gB + (size_t)(i * 32) * K   + kt, Bs + nxt + (i * 32 + wid * 8) * 64);
      }
    }
    s16x8 af[4][2], bf[4][2];
    #pragma unroll
    for (int mf = 0; mf < 4; ++mf) {
      int row = wr * 64 + mf * 16 + lr;
      af[mf][0] = GSWZ(As, cur, row, lk);
      af[mf][1] = GSWZ(As, cur, row, 32 + lk);
    }
    #pragma unroll
    for (int nf = 0; nf < 4; ++nf) {
      int row = wc * 64 + nf * 16 + lr;
      bf[nf][0] = GSWZ(Bs, cur, row, lk);
      bf[nf][1] = GSWZ(Bs, cur, row, 32 + lk);
    }
    #pragma unroll
    for (int mf = 0; mf < 4; ++mf)
      #pragma unroll
      for (int nf = 0; nf < 4; ++nf) {
        acc[mf][nf] = __builtin_amdgcn_mfma_f32_16x16x32_bf16(af[mf][0], bf[nf][0], acc[mf][nf], 0, 0, 0);
        acc[mf][nf] = __builtin_amdgcn_mfma_f32_16x16x32_bf16(af[mf][1], bf[nf][1], acc[mf][nf], 0, 0, 0);
      }
    __syncthreads();
  }
#undef GSWZ
  if (EPI == 3 && n0 >= 2048) {
    #pragma unroll
    for (int mf = 0; mf < 4; ++mf) {
      int row = m0 + wr * 64 + mf * 16 + lg * 4;
      int bb = row >> 10, nn = row & 1023;
      #pragma unroll
      for (int nf = 0; nf < 4; ++nf) {
        int col = n0 + wc * 64 + nf * 16 + lr;
        float bcol = bias[col];
        int hc = col - 2048;
        int hh = hc >> 9, cc = hc & 511;
        unsigned short pk[4];
        #pragma unroll
        for (int r = 0; r < 4; ++r) pk[r] = f2bf(acc[mf][nf][r] + bcol);
        *(s16x4*)(vtout + ((size_t)((bb * 8 + hh) * 512 + cc)) * 1024 + nn) = *(const s16x4*)pk;
      }
    }
    return;
  }
  #pragma unroll
  for (int mf = 0; mf < 4; ++mf)
    #pragma unroll
    for (int nf = 0; nf < 4; ++nf) {
      int col = n0 + wc * 64 + nf * 16 + lr;
      float bcol = bias[col];
      #pragma unroll
      for (int r = 0; r < 4; ++r) {
        int row = m0 + wr * 64 + mf * 16 + lg * 4 + r;
        float v = acc[mf][nf][r] + bcol;
        if (EPI == 1) v = v / (1.0f + __expf(-v));            // swish
        if (EPI == 2) {
          v += res[(size_t)row * N + col];
          ((float*)C)[(size_t)row * ldc + col] = v;
        } else {
          ((unsigned short*)C)[(size_t)row * ldc + col] = f2bf(v);
        }
      }
    }
}

// ---------------- fused differential attention, QBLK=128 ------------------------
// block = (bh, qtile of 128 rows): 512 blocks (2 rounds/CU; halves V re-read).
// 8 waves: wave w owns q-rows w*16..w*16+15 and BOTH softmax types -> pass-1
// stats are wave-local (butterfly leaves every lane with the row sum; no LDS).
// K staged in LDS (XOR-swizzled, both types, 128 cols); no-max softmax; pass2
// recomputes QK bit-identically, P[128][68] dbuf, PV 64 MFMA/iter/wave.
__global__ __launch_bounds__(512) void attn_k(
    const unsigned short* __restrict__ qkv, const unsigned short* __restrict__ vt,
    const float* __restrict__ lamp, unsigned short* __restrict__ aout /* = qkv+2048 */)
{
  const float scale = 0.125f;
  // KP: pass1 = Kd[2][64][128] (16384 u16); pass2 = Ks (8192) + P dbuf (2x8704)
  __shared__ __attribute__((aligned(16))) unsigned short KP[25600];
  int w0 = blockIdx.x;
  int bx = (w0 & 7) * 64 + (w0 >> 3);         // 512 blocks, bijective XCD swizzle
  int bh = bx >> 3, qt = bx & 7;
  int b = bh >> 3, h = bh & 7;
  int tid = threadIdx.x;
  int lane = tid & 63, w = tid >> 6;
  int lr = lane & 15, lg = lane >> 4, lk = lg * 8;
  int qc1 = h * 64, qc2 = 512 + h * 64, kc1 = 1024 + h * 64, kc2 = 1536 + h * 64;
  f32x4 zero = {0.f, 0.f, 0.f, 0.f};
  const unsigned short* kvbase = qkv + (size_t)(b * N_) * DQKV;

  // staging source swizzle (rule 21: inverse-swz source, swz read, linear dest)
  int srw = lane >> 4;                        // 0..3
  int ci0 = (lane & 15) ^ srw;
  int ci1 = (lane & 15) ^ (4 + srw);
  int scol0 = (ci0 < 8) ? (kc1 + ci0 * 8) : (kc2 + (ci0 - 8) * 8);
  int scol1 = (ci1 < 8) ? (kc1 + ci1 * 8) : (kc2 + (ci1 - 8) * 8);

  // Q fragments (both types) for rows qt*128 + w*16 + lr
  s16x8 q1f[2], q2f[2];
  {
    size_t ro = (size_t)(b * N_ + qt * 128 + w * 16 + lr) * DQKV;
    q1f[0] = *(const s16x8*)(qkv + ro + qc1 + lk);
    q1f[1] = *(const s16x8*)(qkv + ro + qc1 + 32 + lk);
    q2f[0] = *(const s16x8*)(qkv + ro + qc2 + lk);
    q2f[1] = *(const s16x8*)(qkv + ro + qc2 + 32 + lk);
  }

#define STAGE_K(Lb, kt)                                                              \
  do {                                                                               \
    gload_lds16(kvbase + (size_t)((kt) * 64 + w * 8 + srw) * DQKV + scol0,           \
                (Lb) + (w * 8) * 128);                                               \
    gload_lds16(kvbase + (size_t)((kt) * 64 + w * 8 + 4 + srw) * DQKV + scol1,       \
                (Lb) + (w * 8 + 4) * 128);                                           \
  } while (0)

#define KREAD(Lb, row, colu) (*(const s16x8*)&(Lb)[(row) * 128 + ((colu) ^ (((row) & 7) * 8))])

  // ---------------- pass 1: l1,l2 for this wave's 16 rows (both types) ----------
  float lp1[4] = {0.f, 0.f, 0.f, 0.f}, lp2[4] = {0.f, 0.f, 0.f, 0.f};
  {
    unsigned short* K0 = KP;
    unsigned short* K1 = KP + 8192;
    STAGE_K(K0, 0);
    __syncthreads();
    for (int kt = 0; kt < 16; ++kt) {
      unsigned short* Lb = (kt & 1) ? K1 : K0;
      STAGE_K((kt & 1) ? K0 : K1, (kt + 1) & 15);  // wraps to 0 at kt=15: warms pass2
      f32x4 s1[4], s2[4];
      #pragma unroll
      for (int nf = 0; nf < 4; ++nf) {
        int row = nf * 16 + lr;
        s16x8 a0 = KREAD(Lb, row, lk);
        s16x8 a1 = KREAD(Lb, row, 32 + lk);
        s16x8 b0 = KREAD(Lb, row, 64 + lk);
        s16x8 b1 = KREAD(Lb, row, 96 + lk);
        f32x4 t1 = __builtin_amdgcn_mfma_f32_16x16x32_bf16(q1f[0], a0, zero, 0, 0, 0);
        s1[nf]   = __builtin_amdgcn_mfma_f32_16x16x32_bf16(q1f[1], a1, t1, 0, 0, 0);
        f32x4 t2 = __builtin_amdgcn_mfma_f32_16x16x32_bf16(q2f[0], b0, zero, 0, 0, 0);
        s2[nf]   = __builtin_amdgcn_mfma_f32_16x16x32_bf16(q2f[1], b1, t2, 0, 0, 0);
      }
      #pragma unroll
      for (int nf = 0; nf < 4; ++nf)
        #pragma unroll
        for (int r = 0; r < 4; ++r) {
          lp1[r] += __expf(s1[nf][r] * scale);
          lp2[r] += __expf(s2[nf][r] * scale);
        }
      __syncthreads();                 // stage drained; all K reads done
    }
    #pragma unroll
    for (int r = 0; r < 4; ++r)
      #pragma unroll
      for (int d = 1; d < 16; d <<= 1) {
        lp1[r] += __shfl_xor(lp1[r], d, 64);
        lp2[r] += __shfl_xor(lp2[r], d, 64);
      }
  }
  float lam = *lamp;
  float r1v[4], r2v[4];
  #pragma unroll
  for (int r = 0; r < 4; ++r) { r1v[r] = 1.f / lp1[r]; r2v[r] = lam / lp2[r]; }

  // ---------------- pass 2: P tiles + PV (Ks pre-warmed with tile 0) ------------
  unsigned short* Ks = KP;
  unsigned short* Pb = KP + 8192;
  f32x4 O[8][4];
  #pragma unroll
  for (int mf = 0; mf < 8; ++mf)
    #pragma unroll
    for (int nf = 0; nf < 4; ++nf) O[mf][nf] = zero;
  for (int kt = 0; kt < 16; ++kt) {
    unsigned short* Pt = Pb + (kt & 1) * 8704;     // [128][68]
    // QK both types, this wave's 16 rows x all 64 kv (bit-identical to pass 1)
    f32x4 s1[4], s2[4];
    #pragma unroll
    for (int nf = 0; nf < 4; ++nf) {
      int row = nf * 16 + lr;
      s16x8 a0 = KREAD(Ks, row, lk);
      s16x8 a1 = KREAD(Ks, row, 32 + lk);
      s16x8 b0 = KREAD(Ks, row, 64 + lk);
      s16x8 b1 = KREAD(Ks, row, 96 + lk);
      f32x4 t1 = __builtin_amdgcn_mfma_f32_16x16x32_bf16(q1f[0], a0, zero, 0, 0, 0);
      s1[nf]   = __builtin_amdgcn_mfma_f32_16x16x32_bf16(q1f[1], a1, t1, 0, 0, 0);
      f32x4 t2 = __builtin_amdgcn_mfma_f32_16x16x32_bf16(q2f[0], b0, zero, 0, 0, 0);
      s2[nf]   = __builtin_amdgcn_mfma_f32_16x16x32_bf16(q2f[1], b1, t2, 0, 0, 0);
    }
    // V prefetch: issued before the barrier, drained by it -> ready for PV
    s16x8 vf[4][2];
    #pragma unroll
    for (int nf = 0; nf < 4; ++nf)
      #pragma unroll
      for (int kq = 0; kq < 2; ++kq)
        vf[nf][kq] = *(const s16x8*)(vt + (size_t)(bh * 512 + w * 64 + nf * 16 + lr) * N_
                                     + kt * 64 + kq * 32 + lk);
    // P = e1/l1 - lam*e2/l2 (no-max exact softmax), rows w*16.., cols nf*16+lr
    #pragma unroll
    for (int nf = 0; nf < 4; ++nf)
      #pragma unroll
      for (int r = 0; r < 4; ++r) {
        float p = __expf(s1[nf][r] * scale) * r1v[r]
                - __expf(s2[nf][r] * scale) * r2v[r];
        Pt[(w * 16 + lg * 4 + r) * 68 + nf * 16 + lr] = f2bf(p);
      }
    __syncthreads();                   // P ready; K consumed by all; vf landed
    if (kt < 15) STAGE_K(Ks, kt + 1);  // safe: all K reads done; drains under PV
    // PV: full P tile [128][64] x wave's 64 v-channels
    #pragma unroll
    for (int mf = 0; mf < 8; ++mf) {
      s16x8 pf0 = *(const s16x8*)&Pt[(mf * 16 + lr) * 68 + lk];
      s16x8 pf1 = *(const s16x8*)&Pt[(mf * 16 + lr) * 68 + 32 + lk];
      #pragma unroll
      for (int nf = 0; nf < 4; ++nf) {
        O[mf][nf] = __builtin_amdgcn_mfma_f32_16x16x32_bf16(pf0, vf[nf][0], O[mf][nf], 0, 0, 0);
        O[mf][nf] = __builtin_amdgcn_mfma_f32_16x16x32_bf16(pf1, vf[nf][1], O[mf][nf], 0, 0, 0);
      }
    }
    __syncthreads();                   // stage(kt+1) drained; P reads done
  }
#undef STAGE_K
#undef KREAD
  // epilogue
  #pragma unroll
  for (int mf = 0; mf < 8; ++mf)
    #pragma unroll
    for (int nf = 0; nf < 4; ++nf) {
      int col = h * 512 + w * 64 + nf * 16 + lr;
      #pragma unroll
      for (int r = 0; r < 4; ++r) {
        int row = b * N_ + qt * 128 + mf * 16 + lg * 4 + r;
        aout[(size_t)row * DQKV + col] = f2bf(O[mf][nf][r]);
      }
    }
}

// ---------------------------------- launcher ------------------------------------
extern "C" void kernel_launch(void* const* d_in, const int* in_sizes, int n_in,
                              void* d_out, int out_size, void* d_ws, size_t ws_size,
                              hipStream_t stream) {
  const float* x    = (const float*)d_in[0];
  const float* t    = (const float*)d_in[1];
  const float* ln1g = (const float*)d_in[2];
  const float* ln1b = (const float*)d_in[3];
  const float* Wqkv = (const float*)d_in[4];
  const float* bqkv = (const float*)d_in[5];
  const float* lam  = (const float*)d_in[6];
  const float* Wm   = (const float*)d_in[7];
  const float* bm   = (const float*)d_in[8];
  const float* Wt1  = (const float*)d_in[9];
  const float* bt1  = (const float*)d_in[10];
  const float* Wt2  = (const float*)d_in[11];
  const float* bt2  = (const float*)d_in[12];
  const float* lnfg = (const float*)d_in[13];
  const float* lnfb = (const float*)d_in[14];
  const float* Wf1  = (const float*)d_in[15];
  const float* bf1  = (const float*)d_in[16];
  const float* Wf2  = (const float*)d_in[17];
  const float* bf2  = (const float*)d_in[18];
  float* out = (float*)d_out;
  char* ws = (char*)d_ws;

  // workspace layout (bytes), ~209 MB total
  unsigned short* qkv   = (unsigned short*)(ws);                  // [8192][6144] bf16 (100.7MB)
  unsigned short* vt    = (unsigned short*)(ws + 100663296ull);   // [64][512][1024] bf16 (67MB)
  float*          x2    = (float*)(ws + 167772160ull);            // [8192][512] f32 (16.8MB)
  unsigned short* xn    = (unsigned short*)(ws + 184549376ull);   // [8192][512] bf16 (xn, then h)
  unsigned short* WqkvT = (unsigned short*)(ws + 193986560ull);   // [6144][512]
  unsigned short* WmT   = (unsigned short*)(ws + 200278016ull);   // [512][4096]
  unsigned short* Wf1T  = (unsigned short*)(ws + 204472320ull);   // [2048][512]
  unsigned short* Wf2T  = (unsigned short*)(ws + 206569472ull);   // [512][2048]
  float*          tp    = (float*)(ws + 208666624ull);            // [8][512]
  unsigned short* ff1s  = qkv;          // alias: qkv dead after attention
  unsigned short* aout  = qkv + 2048;   // alias: attention out over dead V region

  // weights -> bf16 transposed [N][K]
  wtrans_k<<<dim3(DQKV / 32, DIN / 32),  256, 0, stream>>>(Wqkv, WqkvT, DIN, DQKV);
  wtrans_k<<<dim3(DIN / 32, 4096 / 32),  256, 0, stream>>>(Wm,   WmT,   4096, DIN);
  wtrans_k<<<dim3(DEXP / 32, DIN / 32),  256, 0, stream>>>(Wf1,  Wf1T,  DIN, DEXP);
  wtrans_k<<<dim3(DIN / 32, DEXP / 32),  256, 0, stream>>>(Wf2,  Wf2T,  DEXP, DIN);
  // ln1 + time MLP
  ln_k<<<8192, 256, 0, stream>>>(x, nullptr, ln1g, ln1b, xn);
  time_k<<<8, 256, 0, stream>>>(t, Wt1, bt1, Wt2, bt2, tp);
  // qkv GEMM (V columns written directly transposed into vt)
  gemm_bt<3><<<dim3(DQKV / 128, 8192 / 128), 256, 0, stream>>>(
      xn, DIN, WqkvT, bqkv, nullptr, qkv, DQKV, DQKV, DIN, vt);
  // fused two-pass differential attention (QBLK=128)
  attn_k<<<512, 512, 0, stream>>>(qkv, vt, lam, aout);
  // x2 = x + attn_out @ Wm + bm
  gemm_bt<2><<<dim3(DIN / 128, 8192 / 128), 256, 0, stream>>>(
      aout, DQKV, WmT, bm, x, x2, DIN, DIN, 4096, nullptr);
  // h = LN(x2 + tp)
  ln_k<<<8192, 256, 0, stream>>>(x2, tp, lnfg, lnfb, xn);
  // ff1 = swish(h @ Wf1 + bf1)
  gemm_bt<1><<<dim3(DEXP / 128, 8192 / 128), 256, 0, stream>>>(
      xn, DIN, Wf1T, bf1, nullptr, ff1s, DEXP, DEXP, DIN, nullptr);
  // out = x2 + ff1 @ Wf2 + bf2
  gemm_bt<2><<<dim3(DIN / 128, 8192 / 128), 256, 0, stream>>>(
      ff1s, DEXP, Wf2T, bf2, x2, out, DIN, DIN, DEXP, nullptr);
}

// Round 17
// 481.437 us; speedup vs baseline: 1.4247x; 1.0549x over previous
//
#include <hip/hip_runtime.h>

// Problem dims
#define B_    8
#define N_    1024
#define DIN   512
#define H_    8
#define DH    64
#define DQKV  6144   // 2*DQ + 2*DQ + DV = 512+512+512+512+4096
#define DEXP  2048
#define DTIME 256

typedef __attribute__((ext_vector_type(8))) short s16x8;   // 8 bf16 (MFMA A/B frag)
typedef __attribute__((ext_vector_type(4))) short s16x4;
typedef __attribute__((ext_vector_type(4))) float f32x4;   // MFMA C/D frag

__device__ __forceinline__ unsigned short f2bf(float f) {
  unsigned int u = __float_as_uint(f);
  u = (u + 0x7fffu + ((u >> 16) & 1u)) >> 16;   // RNE
  return (unsigned short)u;
}

__device__ __forceinline__ void gload_lds16(const unsigned short* g, unsigned short* l) {
  __builtin_amdgcn_global_load_lds(
      (const __attribute__((address_space(1))) unsigned int*)(g),
      (__attribute__((address_space(3))) unsigned int*)(l), 16, 0, 0);
}

#define WAITV(n) do { asm volatile("s_waitcnt vmcnt(" #n ")" ::: "memory"); \
                      __builtin_amdgcn_sched_barrier(0); } while (0)
#define WAITL0() do { asm volatile("s_waitcnt lgkmcnt(0)" ::: "memory"); \
                      __builtin_amdgcn_sched_barrier(0); } while (0)

// ---------------- LayerNorm (D=512), optional per-batch additive row, bf16 out ----
__global__ __launch_bounds__(256) void ln_k(
    const float* __restrict__ x, const float* __restrict__ add,
    const float* __restrict__ g, const float* __restrict__ bb,
    unsigned short* __restrict__ out)
{
  int row = blockIdx.x;
  int tid = threadIdx.x;
  const float* xr = x + (size_t)row * DIN;
  float v0 = xr[tid], v1 = xr[tid + 256];
  if (add) {
    const float* ar = add + (size_t)(row >> 10) * DIN;   // row/1024 = batch idx
    v0 += ar[tid]; v1 += ar[tid + 256];
  }
  float s = v0 + v1, sq = v0 * v0 + v1 * v1;
  #pragma unroll
  for (int m = 1; m < 64; m <<= 1) { s += __shfl_xor(s, m, 64); sq += __shfl_xor(sq, m, 64); }
  __shared__ float red[8];
  int w = tid >> 6;
  if ((tid & 63) == 0) { red[w] = s; red[4 + w] = sq; }
  __syncthreads();
  s  = red[0] + red[1] + red[2] + red[3];
  sq = red[4] + red[5] + red[6] + red[7];
  float mean = s * (1.0f / DIN);
  float var  = sq * (1.0f / DIN) - mean * mean;
  float rs = rsqrtf(var + 1e-5f);
  unsigned short* orow = out + (size_t)row * DIN;
  orow[tid]       = f2bf((v0 - mean) * rs * g[tid]       + bb[tid]);
  orow[tid + 256] = f2bf((v1 - mean) * rs * g[tid + 256] + bb[tid + 256]);
}

// ---------------- f32 [R][C] -> bf16 [C][R] transpose (weights) ------------------
__global__ __launch_bounds__(256) void wtrans_k(
    const float* __restrict__ in, unsigned short* __restrict__ out, int R, int C)
{
  __shared__ float tile[32][33];
  int tx = threadIdx.x & 31, ty = threadIdx.x >> 5;
  int c0 = blockIdx.x * 32, r0 = blockIdx.y * 32;
  #pragma unroll
  for (int k = 0; k < 4; ++k)
    tile[ty + k * 8][tx] = in[(size_t)(r0 + ty + k * 8) * C + c0 + tx];
  __syncthreads();
  #pragma unroll
  for (int k = 0; k < 4; ++k)
    out[(size_t)(c0 + ty + k * 8) * R + r0 + tx] = f2bf(tile[tx][ty + k * 8]);
}

// ---------------- time MLP: tp[b][512] = swish(t@Wt1+bt1)@Wt2+bt2 ---------------
__global__ __launch_bounds__(256) void time_k(
    const float* __restrict__ t, const float* __restrict__ Wt1, const float* __restrict__ bt1,
    const float* __restrict__ Wt2, const float* __restrict__ bt2, float* __restrict__ tp)
{
  int b = blockIdx.x, tid = threadIdx.x;
  __shared__ float tl[256], hl[256];
  tl[tid] = t[(size_t)b * 256 + tid];
  __syncthreads();
  float a = bt1[tid];
  for (int k = 0; k < 256; ++k) a += tl[k] * Wt1[(size_t)k * 256 + tid];
  hl[tid] = a / (1.0f + __expf(-a));
  __syncthreads();
  for (int j = tid; j < 512; j += 256) {
    float a2 = bt2[j];
    for (int k = 0; k < 256; ++k) a2 += hl[k] * Wt2[(size_t)k * 512 + j];
    tp[(size_t)b * 512 + j] = a2;
  }
}

// ---------------- bf16 MFMA GEMM: C = epi(A @ Bt^T + bias [+res]) ---------------
// 128x128 tile, BK=64, 4 waves; double-buffered LDS, 1 barrier/k-step.
// 32 MFMA per barrier. XOR-swizzle (rule 21): linear dest, pre-swizzled source,
// read colu^((row&7)*8).
template<int EPI>
__global__ __launch_bounds__(256) void gemm_bt(
    const unsigned short* __restrict__ A, int lda,
    const unsigned short* __restrict__ Bt,
    const float* __restrict__ bias, const float* __restrict__ res,
    void* __restrict__ C, int ldc, int N, int K,
    unsigned short* __restrict__ vtout)
{
  __shared__ __attribute__((aligned(16))) unsigned short As[2 * 8192]; // 128x64 x2
  __shared__ __attribute__((aligned(16))) unsigned short Bs[2 * 8192];
  int tid = threadIdx.x;
  int m0 = blockIdx.y * 128, n0 = blockIdx.x * 128;
  int lane = tid & 63, wid = tid >> 6;
  int wr = wid >> 1, wc = wid & 1;
  int lr = lane & 15, lg = lane >> 4, lk = lg * 8;
  f32x4 zero = {0.f, 0.f, 0.f, 0.f};
  f32x4 acc[4][4];
  #pragma unroll
  for (int i = 0; i < 4; ++i)
    #pragma unroll
    for (int j = 0; j < 4; ++j) acc[i][j] = zero;
  // staging: instr i covers rows i*32 + wid*8 + (lane>>3); src col pre-swizzled
  int srow = wid * 8 + (lane >> 3);
  int scol = ((lane & 7) ^ (lane >> 3)) * 8;
  const unsigned short* gA = A  + (size_t)(m0 + srow) * lda + scol;
  const unsigned short* gB = Bt + (size_t)(n0 + srow) * K + scol;
  int nk = K >> 6;
  #pragma unroll
  for (int i = 0; i < 4; ++i) {
    gload_lds16(gA + (size_t)(i * 32) * lda, As + (i * 32 + wid * 8) * 64);
    gload_lds16(gB + (size_t)(i * 32) * K,   Bs + (i * 32 + wid * 8) * 64);
  }
  __syncthreads();
#define GSWZ(Lb, base, row, colu) \
  (*(const s16x8*)&(Lb)[(base) + (row) * 64 + (((colu) ^ (((row) & 7) * 8)))])
  for (int kq = 0; kq < nk; ++kq) {
    int cur = (kq & 1) * 8192;
    if (kq + 1 < nk) {
      int nxt = ((kq + 1) & 1) * 8192;
      int kt = (kq + 1) * 64;
      #pragma unroll
      for (int i = 0; i < 4; ++i) {
        gload_lds16(gA + (size_t)(i * 32) * lda + kt, As + nxt + (i * 32 + wid * 8) * 64);
        gload_lds16(gB + (size_t)(i * 32) * K   + kt, Bs + nxt + (i * 32 + wid * 8) * 64);
      }
    }
    s16x8 af[4][2], bf[4][2];
    #pragma unroll
    for (int mf = 0; mf < 4; ++mf) {
      int row = wr * 64 + mf * 16 + lr;
      af[mf][0] = GSWZ(As, cur, row, lk);
      af[mf][1] = GSWZ(As, cur, row, 32 + lk);
    }
    #pragma unroll
    for (int nf = 0; nf < 4; ++nf) {
      int row = wc * 64 + nf * 16 + lr;
      bf[nf][0] = GSWZ(Bs, cur, row, lk);
      bf[nf][1] = GSWZ(Bs, cur, row, 32 + lk);
    }
    #pragma unroll
    for (int mf = 0; mf < 4; ++mf)
      #pragma unroll
      for (int nf = 0; nf < 4; ++nf) {
        acc[mf][nf] = __builtin_amdgcn_mfma_f32_16x16x32_bf16(af[mf][0], bf[nf][0], acc[mf][nf], 0, 0, 0);
        acc[mf][nf] = __builtin_amdgcn_mfma_f32_16x16x32_bf16(af[mf][1], bf[nf][1], acc[mf][nf], 0, 0, 0);
      }
    __syncthreads();
  }
#undef GSWZ
  if (EPI == 3 && n0 >= 2048) {
    #pragma unroll
    for (int mf = 0; mf < 4; ++mf) {
      int row = m0 + wr * 64 + mf * 16 + lg * 4;
      int bb = row >> 10, nn = row & 1023;
      #pragma unroll
      for (int nf = 0; nf < 4; ++nf) {
        int col = n0 + wc * 64 + nf * 16 + lr;
        float bcol = bias[col];
        int hc = col - 2048;
        int hh = hc >> 9, cc = hc & 511;
        unsigned short pk[4];
        #pragma unroll
        for (int r = 0; r < 4; ++r) pk[r] = f2bf(acc[mf][nf][r] + bcol);
        *(s16x4*)(vtout + ((size_t)((bb * 8 + hh) * 512 + cc)) * 1024 + nn) = *(const s16x4*)pk;
      }
    }
    return;
  }
  #pragma unroll
  for (int mf = 0; mf < 4; ++mf)
    #pragma unroll
    for (int nf = 0; nf < 4; ++nf) {
      int col = n0 + wc * 64 + nf * 16 + lr;
      float bcol = bias[col];
      #pragma unroll
      for (int r = 0; r < 4; ++r) {
        int row = m0 + wr * 64 + mf * 16 + lg * 4 + r;
        float v = acc[mf][nf][r] + bcol;
        if (EPI == 1) v = v / (1.0f + __expf(-v));            // swish
        if (EPI == 2) {
          v += res[(size_t)row * N + col];
          ((float*)C)[(size_t)row * ldc + col] = v;
        } else {
          ((unsigned short*)C)[(size_t)row * ldc + col] = f2bf(v);
        }
      }
    }
}

// ---------------- fused differential attention, QBLK=128, overlapped pass 2 -----
// block = (bh, qtile of 128 rows): 512 blocks. 8 waves; wave w owns q-rows
// w*16..w*16+15, BOTH softmax types (pass-1 stats wave-local, no LDS merge).
// pass 2 pipeline (ONE barrier/iter): iter kt = { stage K(kt+2); issue vf(kt);
// QK(kt+1)+exp -> P[(kt+1)&1]  ||  PV(kt) from P[kt&1] (independent streams,
// exp-VALU overlaps PV-MFMA); WAITV(8) drains stage (vf stays in flight);
// WAITL0; barrier }.
__global__ __launch_bounds__(512) void attn_k(
    const unsigned short* __restrict__ qkv, const unsigned short* __restrict__ vt,
    const float* __restrict__ lamp, unsigned short* __restrict__ aout /* = qkv+2048 */)
{
  const float scale = 0.125f;
  // Kb dbuf: 2 x [64][128] u16 (32KB) ; P dbuf: 2 x [128][68] u16 (34KB)
  __shared__ __attribute__((aligned(16))) unsigned short KP[33792];
  int w0 = blockIdx.x;
  int bx = (w0 & 7) * 64 + (w0 >> 3);         // 512 blocks, bijective XCD swizzle
  int bh = bx >> 3, qt = bx & 7;
  int b = bh >> 3, h = bh & 7;
  int tid = threadIdx.x;
  int lane = tid & 63, w = tid >> 6;
  int lr = lane & 15, lg = lane >> 4, lk = lg * 8;
  int qc1 = h * 64, qc2 = 512 + h * 64, kc1 = 1024 + h * 64, kc2 = 1536 + h * 64;
  f32x4 zero = {0.f, 0.f, 0.f, 0.f};
  const unsigned short* kvbase = qkv + (size_t)(b * N_) * DQKV;

  // staging source swizzle (rule 21: inverse-swz source, swz read, linear dest)
  int srw = lane >> 4;                        // 0..3
  int ci0 = (lane & 15) ^ srw;
  int ci1 = (lane & 15) ^ (4 + srw);
  int scol0 = (ci0 < 8) ? (kc1 + ci0 * 8) : (kc2 + (ci0 - 8) * 8);
  int scol1 = (ci1 < 8) ? (kc1 + ci1 * 8) : (kc2 + (ci1 - 8) * 8);

  // Q fragments (both types) for rows qt*128 + w*16 + lr
  s16x8 q1f[2], q2f[2];
  {
    size_t ro = (size_t)(b * N_ + qt * 128 + w * 16 + lr) * DQKV;
    q1f[0] = *(const s16x8*)(qkv + ro + qc1 + lk);
    q1f[1] = *(const s16x8*)(qkv + ro + qc1 + 32 + lk);
    q2f[0] = *(const s16x8*)(qkv + ro + qc2 + lk);
    q2f[1] = *(const s16x8*)(qkv + ro + qc2 + 32 + lk);
  }

#define STAGE_K(Lb, kt)                                                              \
  do {                                                                               \
    gload_lds16(kvbase + (size_t)((kt) * 64 + w * 8 + srw) * DQKV + scol0,           \
                (Lb) + (w * 8) * 128);                                               \
    gload_lds16(kvbase + (size_t)((kt) * 64 + w * 8 + 4 + srw) * DQKV + scol1,       \
                (Lb) + (w * 8 + 4) * 128);                                           \
  } while (0)

#define KREAD(Lb, row, colu) (*(const s16x8*)&(Lb)[(row) * 128 + ((colu) ^ (((row) & 7) * 8))])

  unsigned short* Kb0 = KP;
  unsigned short* Kb1 = KP + 8192;
  unsigned short* Pb  = KP + 16384;

  // ---------------- pass 1: l1,l2 for this wave's 16 rows (both types) ----------
  float lp1[4] = {0.f, 0.f, 0.f, 0.f}, lp2[4] = {0.f, 0.f, 0.f, 0.f};
  {
    STAGE_K(Kb0, 0);
    __syncthreads();
    for (int kt = 0; kt < 16; ++kt) {
      unsigned short* Lb = (kt & 1) ? Kb1 : Kb0;
      STAGE_K((kt & 1) ? Kb0 : Kb1, (kt + 1) & 15);  // wraps: warms Kb0 w/ tile 0
      f32x4 s1[4], s2[4];
      #pragma unroll
      for (int nf = 0; nf < 4; ++nf) {
        int row = nf * 16 + lr;
        s16x8 a0 = KREAD(Lb, row, lk);
        s16x8 a1 = KREAD(Lb, row, 32 + lk);
        s16x8 b0 = KREAD(Lb, row, 64 + lk);
        s16x8 b1 = KREAD(Lb, row, 96 + lk);
        f32x4 t1 = __builtin_amdgcn_mfma_f32_16x16x32_bf16(q1f[0], a0, zero, 0, 0, 0);
        s1[nf]   = __builtin_amdgcn_mfma_f32_16x16x32_bf16(q1f[1], a1, t1, 0, 0, 0);
        f32x4 t2 = __builtin_amdgcn_mfma_f32_16x16x32_bf16(q2f[0], b0, zero, 0, 0, 0);
        s2[nf]   = __builtin_amdgcn_mfma_f32_16x16x32_bf16(q2f[1], b1, t2, 0, 0, 0);
      }
      #pragma unroll
      for (int nf = 0; nf < 4; ++nf)
        #pragma unroll
        for (int r = 0; r < 4; ++r) {
          lp1[r] += __expf(s1[nf][r] * scale);
          lp2[r] += __expf(s2[nf][r] * scale);
        }
      __syncthreads();                 // stage drained; all K reads done
    }
    #pragma unroll
    for (int r = 0; r < 4; ++r)
      #pragma unroll
      for (int d = 1; d < 16; d <<= 1) {
        lp1[r] += __shfl_xor(lp1[r], d, 64);
        lp2[r] += __shfl_xor(lp2[r], d, 64);
      }
  }
  float lam = *lamp;
  float r1v[4], r2v[4];
  #pragma unroll
  for (int r = 0; r < 4; ++r) { r1v[r] = 1.f / lp1[r]; r2v[r] = lam / lp2[r]; }

  // ---------------- pass 2: overlapped pipeline (Kb0 pre-warmed w/ tile 0) ------
  f32x4 O[8][4];
  #pragma unroll
  for (int mf = 0; mf < 8; ++mf)
    #pragma unroll
    for (int nf = 0; nf < 4; ++nf) O[mf][nf] = zero;

  // helper: QK(tile from Lb) + exp -> P[pb]
  auto qk_to_p = [&](const unsigned short* Lb, unsigned short* Pt) {
    f32x4 s1[4], s2[4];
    #pragma unroll
    for (int nf = 0; nf < 4; ++nf) {
      int row = nf * 16 + lr;
      s16x8 a0 = KREAD(Lb, row, lk);
      s16x8 a1 = KREAD(Lb, row, 32 + lk);
      s16x8 b0 = KREAD(Lb, row, 64 + lk);
      s16x8 b1 = KREAD(Lb, row, 96 + lk);
      f32x4 t1 = __builtin_amdgcn_mfma_f32_16x16x32_bf16(q1f[0], a0, zero, 0, 0, 0);
      s1[nf]   = __builtin_amdgcn_mfma_f32_16x16x32_bf16(q1f[1], a1, t1, 0, 0, 0);
      f32x4 t2 = __builtin_amdgcn_mfma_f32_16x16x32_bf16(q2f[0], b0, zero, 0, 0, 0);
      s2[nf]   = __builtin_amdgcn_mfma_f32_16x16x32_bf16(q2f[1], b1, t2, 0, 0, 0);
    }
    #pragma unroll
    for (int nf = 0; nf < 4; ++nf)
      #pragma unroll
      for (int r = 0; r < 4; ++r) {
        float p = __expf(s1[nf][r] * scale) * r1v[r]
                - __expf(s2[nf][r] * scale) * r2v[r];
        Pt[(w * 16 + lg * 4 + r) * 68 + nf * 16 + lr] = f2bf(p);
      }
  };

  // pre-iter: QK(0) -> P[0]; stage K(1) -> Kb1; drain; barrier
  qk_to_p(Kb0, Pb);
  STAGE_K(Kb1, 1);
  WAITV(0);
  WAITL0();
  __builtin_amdgcn_s_barrier();

  for (int kt = 0; kt < 16; ++kt) {
    unsigned short* Pcur = Pb + (kt & 1) * 8704;
    unsigned short* Pnxt = Pb + ((kt + 1) & 1) * 8704;
    unsigned short* Knxt = ((kt + 1) & 1) ? Kb1 : Kb0;
    unsigned short* Kstg = (kt & 1) ? Kb1 : Kb0;
    int staged = 0;
    if (kt + 2 < 16) { STAGE_K(Kstg, kt + 2); staged = 1; }
    // V for PV(kt): issued now, first use after ~QK+exp latency
    s16x8 vf[4][2];
    #pragma unroll
    for (int nf = 0; nf < 4; ++nf)
      #pragma unroll
      for (int kq = 0; kq < 2; ++kq)
        vf[nf][kq] = *(const s16x8*)(vt + (size_t)(bh * 512 + w * 64 + nf * 16 + lr) * N_
                                     + kt * 64 + kq * 32 + lk);
    // stream A: QK(kt+1)+exp -> P[(kt+1)&1]   (independent of stream B)
    if (kt + 1 < 16) qk_to_p(Knxt, Pnxt);
    // stream B: PV(kt) from P[kt&1] + vf
    __builtin_amdgcn_s_setprio(1);
    #pragma unroll
    for (int mf = 0; mf < 8; ++mf) {
      s16x8 pf0 = *(const s16x8*)&Pcur[(mf * 16 + lr) * 68 + lk];
      s16x8 pf1 = *(const s16x8*)&Pcur[(mf * 16 + lr) * 68 + 32 + lk];
      #pragma unroll
      for (int nf = 0; nf < 4; ++nf) {
        O[mf][nf] = __builtin_amdgcn_mfma_f32_16x16x32_bf16(pf0, vf[nf][0], O[mf][nf], 0, 0, 0);
        O[mf][nf] = __builtin_amdgcn_mfma_f32_16x16x32_bf16(pf1, vf[nf][1], O[mf][nf], 0, 0, 0);
      }
    }
    __builtin_amdgcn_s_setprio(0);
    if (kt < 15) {
      if (staged) { WAITV(8); }        // drain own stage; vf already consumed
      else        { WAITV(0); }
      WAITL0();                        // P writes visible; K/P reads done
      __builtin_amdgcn_s_barrier();
    }
  }
#undef STAGE_K
#undef KREAD
  // epilogue
  #pragma unroll
  for (int mf = 0; mf < 8; ++mf)
    #pragma unroll
    for (int nf = 0; nf < 4; ++nf) {
      int col = h * 512 + w * 64 + nf * 16 + lr;
      #pragma unroll
      for (int r = 0; r < 4; ++r) {
        int row = b * N_ + qt * 128 + mf * 16 + lg * 4 + r;
        aout[(size_t)row * DQKV + col] = f2bf(O[mf][nf][r]);
      }
    }
}

// ---------------------------------- launcher ------------------------------------
extern "C" void kernel_launch(void* const* d_in, const int* in_sizes, int n_in,
                              void* d_out, int out_size, void* d_ws, size_t ws_size,
                              hipStream_t stream) {
  const float* x    = (const float*)d_in[0];
  const float* t    = (const float*)d_in[1];
  const float* ln1g = (const float*)d_in[2];
  const float* ln1b = (const float*)d_in[3];
  const float* Wqkv = (const float*)d_in[4];
  const float* bqkv = (const float*)d_in[5];
  const float* lam  = (const float*)d_in[6];
  const float* Wm   = (const float*)d_in[7];
  const float* bm   = (const float*)d_in[8];
  const float* Wt1  = (const float*)d_in[9];
  const float* bt1  = (const float*)d_in[10];
  const float* Wt2  = (const float*)d_in[11];
  const float* bt2  = (const float*)d_in[12];
  const float* lnfg = (const float*)d_in[13];
  const float* lnfb = (const float*)d_in[14];
  const float* Wf1  = (const float*)d_in[15];
  const float* bf1  = (const float*)d_in[16];
  const float* Wf2  = (const float*)d_in[17];
  const float* bf2  = (const float*)d_in[18];
  float* out = (float*)d_out;
  char* ws = (char*)d_ws;

  // workspace layout (bytes), ~209 MB total
  unsigned short* qkv   = (unsigned short*)(ws);                  // [8192][6144] bf16 (100.7MB)
  unsigned short* vt    = (unsigned short*)(ws + 100663296ull);   // [64][512][1024] bf16 (67MB)
  float*          x2    = (float*)(ws + 167772160ull);            // [8192][512] f32 (16.8MB)
  unsigned short* xn    = (unsigned short*)(ws + 184549376ull);   // [8192][512] bf16 (xn, then h)
  unsigned short* WqkvT = (unsigned short*)(ws + 193986560ull);   // [6144][512]
  unsigned short* WmT   = (unsigned short*)(ws + 200278016ull);   // [512][4096]
  unsigned short* Wf1T  = (unsigned short*)(ws + 204472320ull);   // [2048][512]
  unsigned short* Wf2T  = (unsigned short*)(ws + 206569472ull);   // [512][2048]
  float*          tp    = (float*)(ws + 208666624ull);            // [8][512]
  unsigned short* ff1s  = qkv;          // alias: qkv dead after attention
  unsigned short* aout  = qkv + 2048;   // alias: attention out over dead V region

  // weights -> bf16 transposed [N][K]
  wtrans_k<<<dim3(DQKV / 32, DIN / 32),  256, 0, stream>>>(Wqkv, WqkvT, DIN, DQKV);
  wtrans_k<<<dim3(DIN / 32, 4096 / 32),  256, 0, stream>>>(Wm,   WmT,   4096, DIN);
  wtrans_k<<<dim3(DEXP / 32, DIN / 32),  256, 0, stream>>>(Wf1,  Wf1T,  DIN, DEXP);
  wtrans_k<<<dim3(DIN / 32, DEXP / 32),  256, 0, stream>>>(Wf2,  Wf2T,  DEXP, DIN);
  // ln1 + time MLP
  ln_k<<<8192, 256, 0, stream>>>(x, nullptr, ln1g, ln1b, xn);
  time_k<<<8, 256, 0, stream>>>(t, Wt1, bt1, Wt2, bt2, tp);
  // qkv GEMM (V columns written directly transposed into vt)
  gemm_bt<3><<<dim3(DQKV / 128, 8192 / 128), 256, 0, stream>>>(
      xn, DIN, WqkvT, bqkv, nullptr, qkv, DQKV, DQKV, DIN, vt);
  // fused two-pass differential attention (QBLK=128, overlapped pass 2)
  attn_k<<<512, 512, 0, stream>>>(qkv, vt, lam, aout);
  // x2 = x + attn_out @ Wm + bm
  gemm_bt<2><<<dim3(DIN / 128, 8192 / 128), 256, 0, stream>>>(
      aout, DQKV, WmT, bm, x, x2, DIN, DIN, 4096, nullptr);
  // h = LN(x2 + tp)
  ln_k<<<8192, 256, 0, stream>>>(x2, tp, lnfg, lnfb, xn);
  // ff1 = swish(h @ Wf1 + bf1)
  gemm_bt<1><<<dim3(DEXP / 128, 8192 / 128), 256, 0, stream>>>(
      xn, DIN, Wf1T, bf1, nullptr, ff1s, DEXP, DEXP, DIN, nullptr);
  // out = x2 + ff1 @ Wf2 + bf2
  gemm_bt<2><<<dim3(DIN / 128, 8192 / 128), 256, 0, stream>>>(
      ff1s, DEXP, Wf2T, bf2, x2, out, DIN, DIN, DEXP, nullptr);
}